// Round 1
// baseline (10239.431 us; speedup 1.0000x reference)
//
#include <hip/hip_runtime.h>
#include <hip/hip_bf16.h>

using bf16 = __hip_bfloat16;
typedef short v8s __attribute__((ext_vector_type(8)));   // 8 bf16 = 4 VGPRs
typedef float v4f __attribute__((ext_vector_type(4)));   // MFMA C/D frag

__device__ __forceinline__ float sigmoidf_(float x) {
    return 1.0f / (1.0f + __expf(-x));
}
__device__ __forceinline__ float tanhf_(float x) {
    return 1.0f - 2.0f / (__expf(2.0f * x) + 1.0f);
}
__device__ __forceinline__ unsigned short bfbits(float f) {
    bf16 h = __float2bfloat16(f);
    return *reinterpret_cast<unsigned short*>(&h);
}

// ---------------- fp32 -> bf16 converter ----------------
__global__ void f2b_kernel(const float* __restrict__ s, bf16* __restrict__ d, int n) {
    int idx = blockIdx.x * blockDim.x + threadIdx.x;
    int stride = gridDim.x * blockDim.x;
    for (int i = idx * 4; i < n; i += stride * 4) {
        float4 v = *reinterpret_cast<const float4*>(s + i);
        ushort4 u;
        u.x = bfbits(v.x); u.y = bfbits(v.y); u.z = bfbits(v.z); u.w = bfbits(v.w);
        *reinterpret_cast<ushort4*>(d + i) = u;
    }
}

// ---------------- init states ----------------
// eh/ec: [L,B,H] fp32. hf/cf: [L*B*H] fp32. hbf: [L][2][B*H] bf16 (slot 0 init).
__global__ void init_state_kernel(const float* __restrict__ eh, const float* __restrict__ ec,
                                  float* __restrict__ hf, float* __restrict__ cf,
                                  bf16* __restrict__ hbf) {
    int idx = blockIdx.x * blockDim.x + threadIdx.x;
    if (idx >= 2 * 32 * 512) return;
    int l = idx >> 14;          // / 16384
    int rem = idx & 16383;
    hf[idx] = eh[idx];
    cf[idx] = ec[idx];
    hbf[(l * 2 + 0) * 16384 + rem] = __float2bfloat16(eh[idx]);
}

// ---------------- tail: final states -> d_out ----------------
__global__ void tail_kernel(const float* __restrict__ hf, const float* __restrict__ cf,
                            float* __restrict__ out) {
    int idx = blockIdx.x * blockDim.x + threadIdx.x;
    if (idx >= 2 * 32 * 512) return;
    out[1048576 + idx] = hf[idx];
    out[1048576 + 32768 + idx] = cf[idx];
}

// ---------------- bf16 MFMA GEMM: C[M,N] = A[M,K] @ W[N,K]^T (+bias) ----------------
// 64x64 tile, BK=64, 4 waves: wave w computes rows [w*16, w*16+16) x all 64 cols.
__global__ __launch_bounds__(256) void gemm_bt(
    const bf16* __restrict__ A, const bf16* __restrict__ W,
    const float* __restrict__ bias,
    float* __restrict__ Cf, bf16* __restrict__ Cb,
    int M, int N, int K) {
    __shared__ __align__(16) bf16 As[64][72];
    __shared__ __align__(16) bf16 Bs[64][72];
    const int tid = threadIdx.x;
    const int wave = tid >> 6, lane = tid & 63;
    const int lr = lane & 15, lq = lane >> 4;
    const int m0 = blockIdx.y * 64, n0 = blockIdx.x * 64;

    v4f acc[4];
#pragma unroll
    for (int n = 0; n < 4; ++n) acc[n] = (v4f){0.f, 0.f, 0.f, 0.f};

    for (int k0 = 0; k0 < K; k0 += 64) {
        __syncthreads();
#pragma unroll
        for (int c = tid; c < 512; c += 256) {
            int row = c >> 3, c8 = (c & 7) * 8;
            *reinterpret_cast<v8s*>(&As[row][c8]) =
                *reinterpret_cast<const v8s*>(A + (size_t)(m0 + row) * K + k0 + c8);
            *reinterpret_cast<v8s*>(&Bs[row][c8]) =
                *reinterpret_cast<const v8s*>(W + (size_t)(n0 + row) * K + k0 + c8);
        }
        __syncthreads();
#pragma unroll
        for (int kk = 0; kk < 2; ++kk) {
            v8s a = *reinterpret_cast<const v8s*>(&As[wave * 16 + lr][kk * 32 + lq * 8]);
#pragma unroll
            for (int n = 0; n < 4; ++n) {
                v8s b = *reinterpret_cast<const v8s*>(&Bs[n * 16 + lr][kk * 32 + lq * 8]);
                acc[n] = __builtin_amdgcn_mfma_f32_16x16x32_bf16(a, b, acc[n], 0, 0, 0);
            }
        }
    }
#pragma unroll
    for (int n = 0; n < 4; ++n) {
        int col = n0 + n * 16 + lr;
        float bv = bias ? bias[col] : 0.0f;
#pragma unroll
        for (int r = 0; r < 4; ++r) {
            int row = m0 + wave * 16 + lq * 4 + r;
            float v = acc[n][r] + bv;
            if (Cf) Cf[(size_t)row * N + col] = v;
            if (Cb) Cb[(size_t)row * N + col] = __float2bfloat16(v);
        }
    }
}

// ---------------- fused LSTM step ----------------
// grid = 32 WGs x 256 thr. WG j owns hidden cols [j*16, j*16+16).
// Wave w computes gate w's 16 cols for all 32 batches via MFMA (K=512),
// then pointwise through LDS. Gate order: i,f,g,o.
__global__ __launch_bounds__(256) void lstm_step(
    const bf16* __restrict__ hin,       // [32][512]
    bf16* __restrict__ hout,            // [32][512]
    float* __restrict__ hf,             // [32][512] fp32 h state
    float* __restrict__ cf,             // [32][512] fp32 c state
    const bf16* __restrict__ Whh,       // [2048][512]
    const float* __restrict__ xpf,      // fp32 xproj base for this t (or null)
    const bf16* __restrict__ xpb,       // bf16 xproj base for this t (or null)
    long xp_stride_b,
    const float* __restrict__ bih, const float* __restrict__ bhh,
    bf16* __restrict__ seq, long seq_stride_b,   // optional bf16 h sequence out
    float* __restrict__ outf, long out_stride_b) // optional fp32 h sequence out
{
    __shared__ float gs[4][32][16];
    const int tid = threadIdx.x;
    const int wave = tid >> 6, lane = tid & 63;
    const int lr = lane & 15, lq = lane >> 4;
    const int hc0 = blockIdx.x * 16;

    const bf16* wrow = Whh + (size_t)(wave * 512 + hc0 + lr) * 512 + lq * 8;
    const bf16* arow = hin + (size_t)lr * 512 + lq * 8;

    v4f acc0 = (v4f){0.f, 0.f, 0.f, 0.f};
    v4f acc1 = (v4f){0.f, 0.f, 0.f, 0.f};
#pragma unroll 4
    for (int kk = 0; kk < 16; ++kk) {
        v8s b  = *reinterpret_cast<const v8s*>(wrow + kk * 32);
        v8s a0 = *reinterpret_cast<const v8s*>(arow + kk * 32);
        v8s a1 = *reinterpret_cast<const v8s*>(arow + 16 * 512 + kk * 32);
        acc0 = __builtin_amdgcn_mfma_f32_16x16x32_bf16(a0, b, acc0, 0, 0, 0);
        acc1 = __builtin_amdgcn_mfma_f32_16x16x32_bf16(a1, b, acc1, 0, 0, 0);
    }
#pragma unroll
    for (int r = 0; r < 4; ++r) {
        gs[wave][lq * 4 + r][lr]      = acc0[r];
        gs[wave][16 + lq * 4 + r][lr] = acc1[r];
    }
    __syncthreads();

#pragma unroll
    for (int i = tid; i < 512; i += 256) {
        int b = i >> 4, col = i & 15;
        int gc = hc0 + col;
        float xi, xf, xg, xo;
        if (xpf) {
            const float* xp = xpf + (size_t)b * xp_stride_b;
            xi = xp[gc]; xf = xp[512 + gc]; xg = xp[1024 + gc]; xo = xp[1536 + gc];
        } else {
            const bf16* xp = xpb + (size_t)b * xp_stride_b;
            xi = __bfloat162float(xp[gc]);
            xf = __bfloat162float(xp[512 + gc]);
            xg = __bfloat162float(xp[1024 + gc]);
            xo = __bfloat162float(xp[1536 + gc]);
        }
        float gi = gs[0][b][col] + xi + bih[gc] + bhh[gc];
        float gfv = gs[1][b][col] + xf + bih[512 + gc] + bhh[512 + gc];
        float gg = gs[2][b][col] + xg + bih[1024 + gc] + bhh[1024 + gc];
        float go = gs[3][b][col] + xo + bih[1536 + gc] + bhh[1536 + gc];

        size_t sidx = (size_t)b * 512 + gc;
        float c_old = cf[sidx];
        float c_new = sigmoidf_(gfv) * c_old + sigmoidf_(gi) * tanhf_(gg);
        float h = sigmoidf_(go) * tanhf_(c_new);
        cf[sidx] = c_new;
        hf[sidx] = h;
        hout[sidx] = __float2bfloat16(h);
        if (seq)  seq[(size_t)b * seq_stride_b + gc] = __float2bfloat16(h);
        if (outf) outf[(size_t)b * out_stride_b + gc] = h;
    }
}

// ---------------- host orchestration ----------------
extern "C" void kernel_launch(void* const* d_in, const int* in_sizes, int n_in,
                              void* d_out, int out_size, void* d_ws, size_t ws_size,
                              hipStream_t stream) {
    constexpr int B = 32, S = 512, F = 64, I = 512, H = 512, G = 2048;

    const float* x    = (const float*)d_in[0];
    const float* fut  = (const float*)d_in[1];
    const float* eh   = (const float*)d_in[2];
    const float* ec   = (const float*)d_in[3];
    const float* fc_w = (const float*)d_in[4];
    const float* fc_b = (const float*)d_in[5];
    const float* ewih = (const float*)d_in[6];
    const float* ewhh = (const float*)d_in[7];
    const float* ebih = (const float*)d_in[8];
    const float* ebhh = (const float*)d_in[9];
    const float* dwih = (const float*)d_in[10];
    const float* dwhh = (const float*)d_in[11];
    const float* dbih = (const float*)d_in[12];
    const float* dbhh = (const float*)d_in[13];
    float* out = (float*)d_out;

    char* ws = (char*)d_ws;
    size_t off = 0;
    auto alloc = [&](size_t bytes) -> char* {
        char* p = ws + off;
        off += (bytes + 255) & ~(size_t)255;
        return p;
    };

    bf16* x_bf    = (bf16*)alloc((size_t)B * S * I * 2);
    bf16* fut_bf  = (bf16*)alloc((size_t)B * F * I * 2);
    bf16* fcw_bf  = (bf16*)alloc((size_t)H * I * 2);
    bf16* ewih_bf = (bf16*)alloc((size_t)2 * G * H * 2);
    bf16* ewhh_bf = (bf16*)alloc((size_t)2 * G * H * 2);
    bf16* dwih_bf = (bf16*)alloc((size_t)2 * G * H * 2);
    bf16* dwhh_bf = (bf16*)alloc((size_t)2 * G * H * 2);
    bf16* xt_bf   = (bf16*)alloc((size_t)B * S * H * 2);
    bf16* h0seq   = (bf16*)alloc((size_t)B * S * H * 2);
    bf16* hD0seq  = (bf16*)alloc((size_t)B * F * H * 2);
    bf16* hbf     = (bf16*)alloc((size_t)2 * 2 * B * H * 2);  // [L][slot][B*H]
    float* hf     = (float*)alloc((size_t)2 * B * H * 4);
    float* cf     = (float*)alloc((size_t)2 * B * H * 4);

    // Xproj: fp32 if workspace allows, else bf16
    size_t xp32_bytes = (size_t)B * S * G * 4;
    bool xp32 = (ws_size - off) >= xp32_bytes + 4096;
    float* Xf = nullptr; bf16* Xb = nullptr;
    if (xp32) Xf = (float*)alloc(xp32_bytes);
    else      Xb = (bf16*)alloc((size_t)B * S * G * 2);

    auto cvt = [&](const float* s, bf16* d, int n) {
        int blocks = (n / 4 + 255) / 256;
        if (blocks > 4096) blocks = 4096;
        f2b_kernel<<<blocks, 256, 0, stream>>>(s, d, n);
    };
    cvt(x, x_bf, B * S * I);
    cvt(fut, fut_bf, B * F * I);
    cvt(fc_w, fcw_bf, H * I);
    cvt(ewih, ewih_bf, 2 * G * H);
    cvt(ewhh, ewhh_bf, 2 * G * H);
    cvt(dwih, dwih_bf, 2 * G * H);
    cvt(dwhh, dwhh_bf, 2 * G * H);

    init_state_kernel<<<128, 256, 0, stream>>>(eh, ec, hf, cf, hbf);

    auto gemm = [&](const bf16* A, const bf16* W, const float* bias,
                    float* Cf_, bf16* Cb_, int M, int N, int K) {
        gemm_bt<<<dim3(N / 64, M / 64), 256, 0, stream>>>(A, W, bias, Cf_, Cb_, M, N, K);
    };

    // FC: xt = bf16(x @ fc_w^T + fc_b)
    gemm(x_bf, fcw_bf, fc_b, nullptr, xt_bf, B * S, H, I);

    auto run_layer = [&](const bf16* Whh_l, const float* bih_l, const float* bhh_l,
                         int layer, int T, long xp_stride,
                         bf16* seq_base, long seq_stride,
                         float* out_base, long out_stride) {
        for (int t = 0; t < T; ++t) {
            lstm_step<<<32, 256, 0, stream>>>(
                hbf + (size_t)(layer * 2 + (t & 1)) * (B * H),
                hbf + (size_t)(layer * 2 + ((t + 1) & 1)) * (B * H),
                hf + (size_t)layer * B * H, cf + (size_t)layer * B * H,
                Whh_l,
                Xf ? Xf + (size_t)t * G : nullptr,
                Xb ? Xb + (size_t)t * G : nullptr,
                xp_stride,
                bih_l, bhh_l,
                seq_base ? seq_base + (size_t)t * H : nullptr, seq_stride,
                out_base ? out_base + (size_t)t * H : nullptr, out_stride);
        }
    };

    // ---- Encoder layer 0 ----
    gemm(xt_bf, ewih_bf, nullptr, Xf, Xb, B * S, G, H);
    run_layer(ewhh_bf, ebih, ebhh, 0, S, (long)S * G, h0seq, (long)S * H, nullptr, 0);

    // ---- Encoder layer 1 ---- (output sequence discarded; only final state matters)
    gemm(h0seq, ewih_bf + (size_t)G * H, nullptr, Xf, Xb, B * S, G, H);
    run_layer(ewhh_bf + (size_t)G * H, ebih + G, ebhh + G, 1, S, (long)S * G,
              nullptr, 0, nullptr, 0);

    // ---- Decoder layer 0 ---- (initial state = encoder finals, already in hf/cf/hbf slot0)
    gemm(fut_bf, dwih_bf, nullptr, Xf, Xb, B * F, G, H);
    run_layer(dwhh_bf, dbih, dbhh, 0, F, (long)F * G, hD0seq, (long)F * H, nullptr, 0);

    // ---- Decoder layer 1 ---- writes dec_out directly
    gemm(hD0seq, dwih_bf + (size_t)G * H, nullptr, Xf, Xb, B * F, G, H);
    run_layer(dwhh_bf + (size_t)G * H, dbih + G, dbhh + G, 1, F, (long)F * G,
              nullptr, 0, out, (long)F * H);

    // ---- Final decoder states ----
    tail_kernel<<<128, 256, 0, stream>>>(hf, cf, out);
}